// Round 2
// baseline (1682.564 us; speedup 1.0000x reference)
//
#include <hip/hip_runtime.h>
#include <math.h>

// SimpleGCDEC: z = adj @ (x @ W) + b ; q = student-t soft assignment
// N=10000, NFEAT=3000, NHID=32, K=10, ALPHA=0.2
//
// Streaming split-K GEMM: A (x / adj) goes global->registers directly
// (used once, no LDS, no per-chunk barrier); only B (W / support) is
// staged in LDS (one barrier per 320 k).
// R1 change: thread tile 2 rows x 8 cols (TRB=128) + __launch_bounds__(256,4)
// to force VGPR<=128 -> 4 waves/SIMD (R0 was 168 VGPR -> 2 waves/SIMD,
// occupancy 11%, latency exposed).

#define NH   32      // NHID
#define SUBK 320     // B rows staged per LDS round (40960 B)
#define TRB  128     // rows per block

__device__ __forceinline__ void fma8x2(const float4* __restrict__ bs, int jg2,
                                       const float4* a0, const float4* a1,
                                       float acc[2][8])
{
#pragma unroll
    for (int u = 0; u < 2; ++u) {
#pragma unroll
        for (int t = 0; t < 4; ++t) {
            float4 b0 = bs[(u * 4 + t) * 8 + jg2];
            float4 b1 = bs[(u * 4 + t) * 8 + jg2 + 1];
#pragma unroll
            for (int m = 0; m < 2; ++m) {
                float4 am = u ? a1[m] : a0[m];
                float av = (t == 0) ? am.x : (t == 1) ? am.y
                         : (t == 2) ? am.z : am.w;
                acc[m][0] += av * b0.x;
                acc[m][1] += av * b0.y;
                acc[m][2] += av * b0.z;
                acc[m][3] += av * b0.w;
                acc[m][4] += av * b1.x;
                acc[m][5] += av * b1.y;
                acc[m][6] += av * b1.z;
                acc[m][7] += av * b1.w;
            }
        }
    }
}

__global__ __launch_bounds__(256, 4) void gemm_stream32(
    const float* __restrict__ A,   // [M][K], streamed
    const float* __restrict__ B,   // [K][32], LDS-staged
    float* __restrict__ outp,      // [nsplit][M][32] partials
    int M, int K, int CH)          // CH = k-range per split, multiple of 8
{
    __shared__ float Bs[SUBK * NH];          // 40960 B

    const int tid     = threadIdx.x;
    const int rowslot = tid >> 2;            // 0..63
    const int jg      = tid & 3;             // 0..3 (cols jg*8..+7)
    const int jg2     = jg << 1;
    const int row0    = blockIdx.x * TRB;
    const int sy      = blockIdx.y;
    const int k0      = sy * CH;
    const int kspl    = min(CH, K - k0);     // > 0, multiple of 8 (K%8==0)

    // per-thread A row pointers (row-clamped; stores are guarded below)
    const float* ap[2];
#pragma unroll
    for (int m = 0; m < 2; ++m) {
        int r = row0 + rowslot + (m << 6);
        if (r > M - 1) r = M - 1;
        ap[m] = A + (size_t)r * K + k0;
    }

    float acc[2][8];
#pragma unroll
    for (int m = 0; m < 2; ++m)
#pragma unroll
        for (int j = 0; j < 8; ++j) acc[m][j] = 0.0f;

    for (int kb = 0; kb < kspl; kb += SUBK) {
        const int kcnt = min(SUBK, kspl - kb);   // multiple of 8

        // ---- stage B sub-block: kcnt rows x 32 cols, contiguous float4 copy
        {
            const float4* src = (const float4*)(B + (size_t)(k0 + kb) * NH);
            float4* dst = (float4*)Bs;
            for (int i = tid; i < kcnt * 8; i += 256) dst[i] = src[i];
        }
        __syncthreads();

        // ---- stream A from global with 8-k ping-pong prefetch
        float4 A0[2], A1[2], B0[2], B1[2];
#pragma unroll
        for (int m = 0; m < 2; ++m) {
            A0[m] = *(const float4*)(ap[m] + kb);
            A1[m] = *(const float4*)(ap[m] + kb + 4);
        }

        int kk = 0;
        for (; kk + 16 <= kcnt; kk += 16) {
            // prefetch second half (kk+8)
#pragma unroll
            for (int m = 0; m < 2; ++m) {
                B0[m] = *(const float4*)(ap[m] + kb + kk + 8);
                B1[m] = *(const float4*)(ap[m] + kb + kk + 12);
            }
            fma8x2(((const float4*)Bs) + kk * 8, jg2, A0, A1, acc);
            // prefetch next iteration's first half (kk+16)
            if (kk + 16 < kcnt) {
#pragma unroll
                for (int m = 0; m < 2; ++m) {
                    A0[m] = *(const float4*)(ap[m] + kb + kk + 16);
                    A1[m] = *(const float4*)(ap[m] + kb + kk + 20);
                }
            }
            fma8x2(((const float4*)Bs) + (kk + 8) * 8, jg2, B0, B1, acc);
        }
        if (kk < kcnt) {   // 8-k tail
            fma8x2(((const float4*)Bs) + kk * 8, jg2, A0, A1, acc);
        }
        __syncthreads();
    }

    // ---- store partials (coalesced: 4 lanes cover a 128 B row)
    float* op = outp + (size_t)sy * M * NH;
#pragma unroll
    for (int m = 0; m < 2; ++m) {
        int gr = row0 + rowslot + (m << 6);
        if (gr < M) {
            float4 v0 = make_float4(acc[m][0], acc[m][1], acc[m][2], acc[m][3]);
            float4 v1 = make_float4(acc[m][4], acc[m][5], acc[m][6], acc[m][7]);
            *(float4*)(op + (size_t)gr * NH + (jg << 3))     = v0;
            *(float4*)(op + (size_t)gr * NH + (jg << 3) + 4) = v1;
        }
    }
}

__global__ __launch_bounds__(256) void reduce_add(
    const float* __restrict__ parts,  // [nsplit][total4] float4
    const float* __restrict__ bias,   // [32] or nullptr
    float* __restrict__ out,          // [total4] float4
    int total4, int nsplit)
{
    int i = blockIdx.x * blockDim.x + threadIdx.x;
    if (i >= total4) return;
    float4 s = make_float4(0.f, 0.f, 0.f, 0.f);
    for (int p = 0; p < nsplit; ++p) {
        float4 v = ((const float4*)parts)[(size_t)p * total4 + i];
        s.x += v.x; s.y += v.y; s.z += v.z; s.w += v.w;
    }
    if (bias) {
        float4 bv = ((const float4*)bias)[i & 7];   // f4 slot within 32-wide row
        s.x += bv.x; s.y += bv.y; s.z += bv.z; s.w += bv.w;
    }
    ((float4*)out)[i] = s;
}

__global__ __launch_bounds__(256) void qkern(
    const float* __restrict__ z,   // [N][32]
    const float* __restrict__ mu,  // [10][32]
    float* __restrict__ q,         // [N][10]
    int N)
{
    const int tid  = threadIdx.x;
    const int lane = tid & 31;
    const int i    = blockIdx.x * 8 + (tid >> 5);
    if (i >= N) return;

    float zv = z[i * 32 + lane];
    float qm = 0.f, qsum = 0.f;
#pragma unroll
    for (int c = 0; c < 10; ++c) {
        float d = zv - mu[c * 32 + lane];
        float p = d * d;
#pragma unroll
        for (int m = 16; m >= 1; m >>= 1) p += __shfl_xor(p, m, 32);
        // q = (1 + d2/alpha + 1e-8)^-(alpha+1) / 2,  alpha = 0.2
        float t  = 1.0f + p * 5.0f + 1e-8f;
        float qc = powf(t, -1.2f) * 0.5f;
        qsum += qc;
        if (lane == c) qm = qc;
    }
    if (lane < 10) q[i * 10 + lane] = qm / qsum;
}

extern "C" void kernel_launch(void* const* d_in, const int* in_sizes, int n_in,
                              void* d_out, int out_size, void* d_ws, size_t ws_size,
                              hipStream_t stream)
{
    const float* x   = (const float*)d_in[0];   // [10000][3000]
    const float* adj = (const float*)d_in[1];   // [10000][10000]
    const float* W   = (const float*)d_in[2];   // [3000][32]
    const float* b   = (const float*)d_in[3];   // [32]
    const float* mu  = (const float*)d_in[4];   // [10][32]

    const int N = 10000, NFEAT = 3000;
    float* z_out = (float*)d_out;               // [10000][32]
    float* q_out = (float*)d_out + N * NH;      // [10000][10]

    // split-K factor: 32 if workspace allows (42.24 MB), else 16
    const size_t need32 = (size_t)(32 + 1) * N * NH * sizeof(float);
    const int nsplit = (ws_size >= need32) ? 32 : 16;

    float* ws_part    = (float*)d_ws;                            // nsplit*320000
    float* ws_support = (float*)d_ws + (size_t)nsplit * N * NH;  // 320000

    const int total4  = N * NH / 4;             // 80000
    const int rowBlks = (N + TRB - 1) / TRB;    // 79
    const int redBlks = (total4 + 255) / 256;   // 313

    // k-chunk per split, rounded up to a multiple of 8
    const int ch1 = ((NFEAT + nsplit - 1) / nsplit + 7) & ~7;
    const int ch2 = ((N     + nsplit - 1) / nsplit + 7) & ~7;

    // 1) support partials = x @ W
    gemm_stream32<<<dim3(rowBlks, nsplit), 256, 0, stream>>>(
        x, W, ws_part, N, NFEAT, ch1);
    // 2) support = sum partials
    reduce_add<<<redBlks, 256, 0, stream>>>(ws_part, nullptr, ws_support, total4, nsplit);
    // 3) z partials = adj @ support
    gemm_stream32<<<dim3(rowBlks, nsplit), 256, 0, stream>>>(
        adj, ws_support, ws_part, N, N, ch2);
    // 4) z = sum partials + b  -> d_out
    reduce_add<<<redBlks, 256, 0, stream>>>(ws_part, b, z_out, total4, nsplit);
    // 5) q from z -> d_out + 320000
    qkern<<<(N + 7) / 8, 256, 0, stream>>>(z_out, mu, q_out, N);
}

// Round 4
// 878.957 us; speedup vs baseline: 1.9143x; 1.9143x over previous
//
#include <hip/hip_runtime.h>
#include <math.h>

// SimpleGCDEC: z = adj @ (x @ W) + b ; q = student-t soft assignment
// N=10000, NFEAT=3000, NHID=32, K=10, ALPHA=0.2
//
// Streaming split-K GEMM: A (x / adj) global->registers (used once, no LDS
// for A); B (W / support) staged in LDS, 160 rows per round (20 KB).
// R3 (resubmit; R3 bench was an infra failure): thread tile 4 rows x 4 cols
// (TRB=128) -> 1 ds_read_b128 : 16 FMA (halves LDS-pipe pressure vs 2x8),
// plain __launch_bounds__(256) (R2's (256,4) forced VGPR=64 -> spills).

#define NH   32      // NHID
#define SUBK 160     // B rows staged per LDS round (20480 B)
#define TRB  128     // rows per block

__device__ __forceinline__ void fma4x4(const float4* __restrict__ bs, int jg,
                                       const float4* a0, const float4* a1,
                                       float acc[4][4])
{
#pragma unroll
    for (int u = 0; u < 2; ++u) {
#pragma unroll
        for (int t = 0; t < 4; ++t) {
            float4 b = bs[(u * 4 + t) * 8 + jg];
#pragma unroll
            for (int m = 0; m < 4; ++m) {
                float4 am = u ? a1[m] : a0[m];
                float av = (t == 0) ? am.x : (t == 1) ? am.y
                         : (t == 2) ? am.z : am.w;
                acc[m][0] += av * b.x;
                acc[m][1] += av * b.y;
                acc[m][2] += av * b.z;
                acc[m][3] += av * b.w;
            }
        }
    }
}

__global__ __launch_bounds__(256) void gemm_stream32(
    const float* __restrict__ A,   // [M][K], streamed
    const float* __restrict__ B,   // [K][32], LDS-staged
    float* __restrict__ outp,      // [nsplit][M][32] partials
    int M, int K, int CH)          // CH = k-range per split, multiple of 8
{
    __shared__ float Bs[SUBK * NH];          // 20480 B

    const int tid     = threadIdx.x;
    const int rowslot = tid >> 3;            // 0..31
    const int jg      = tid & 7;             // 0..7 (cols jg*4..+3)
    const int row0    = blockIdx.x * TRB;
    const int sy      = blockIdx.y;
    const int k0      = sy * CH;
    const int kspl    = min(CH, K - k0);     // > 0, multiple of 8

    // per-thread A row pointers (row-clamped; stores are guarded below)
    const float* ap[4];
#pragma unroll
    for (int m = 0; m < 4; ++m) {
        int r = row0 + rowslot + (m << 5);
        if (r > M - 1) r = M - 1;
        ap[m] = A + (size_t)r * K + k0;
    }

    float acc[4][4];
#pragma unroll
    for (int m = 0; m < 4; ++m)
#pragma unroll
        for (int j = 0; j < 4; ++j) acc[m][j] = 0.0f;

    for (int kb = 0; kb < kspl; kb += SUBK) {
        const int kcnt = min(SUBK, kspl - kb);   // multiple of 8

        // ---- stage B sub-block: kcnt rows x 32 cols, contiguous float4 copy
        {
            const float4* src = (const float4*)(B + (size_t)(k0 + kb) * NH);
            float4* dst = (float4*)Bs;
            for (int i = tid; i < kcnt * 8; i += 256) dst[i] = src[i];
        }
        __syncthreads();

        // ---- stream A from global with 8-k ping-pong prefetch
        float4 A0[4], A1[4], P0[4], P1[4];
#pragma unroll
        for (int m = 0; m < 4; ++m) {
            A0[m] = *(const float4*)(ap[m] + kb);
            A1[m] = *(const float4*)(ap[m] + kb + 4);
        }

        int kk = 0;
        for (; kk + 16 <= kcnt; kk += 16) {
            // prefetch second half (kk+8)
#pragma unroll
            for (int m = 0; m < 4; ++m) {
                P0[m] = *(const float4*)(ap[m] + kb + kk + 8);
                P1[m] = *(const float4*)(ap[m] + kb + kk + 12);
            }
            fma4x4(((const float4*)Bs) + kk * 8, jg, A0, A1, acc);
            // prefetch next iteration's first half (kk+16)
            if (kk + 16 < kcnt) {
#pragma unroll
                for (int m = 0; m < 4; ++m) {
                    A0[m] = *(const float4*)(ap[m] + kb + kk + 16);
                    A1[m] = *(const float4*)(ap[m] + kb + kk + 20);
                }
            }
            fma4x4(((const float4*)Bs) + (kk + 8) * 8, jg, P0, P1, acc);
        }
        if (kk < kcnt) {   // 8-k tail
            fma4x4(((const float4*)Bs) + kk * 8, jg, A0, A1, acc);
        }
        __syncthreads();
    }

    // ---- store partials (coalesced: one 1024 B wave-store per m)
    float* op = outp + (size_t)sy * M * NH;
#pragma unroll
    for (int m = 0; m < 4; ++m) {
        int gr = row0 + rowslot + (m << 5);
        if (gr < M) {
            float4 v = make_float4(acc[m][0], acc[m][1], acc[m][2], acc[m][3]);
            *(float4*)(op + (size_t)gr * NH + (jg << 2)) = v;
        }
    }
}

__global__ __launch_bounds__(256) void reduce_add(
    const float* __restrict__ parts,  // [nsplit][total4] float4
    const float* __restrict__ bias,   // [32] or nullptr
    float* __restrict__ out,          // [total4] float4
    int total4, int nsplit)
{
    int i = blockIdx.x * blockDim.x + threadIdx.x;
    if (i >= total4) return;
    float4 s = make_float4(0.f, 0.f, 0.f, 0.f);
    for (int p = 0; p < nsplit; ++p) {
        float4 v = ((const float4*)parts)[(size_t)p * total4 + i];
        s.x += v.x; s.y += v.y; s.z += v.z; s.w += v.w;
    }
    if (bias) {
        float4 bv = ((const float4*)bias)[i & 7];   // f4 slot within 32-wide row
        s.x += bv.x; s.y += bv.y; s.z += bv.z; s.w += bv.w;
    }
    ((float4*)out)[i] = s;
}

__global__ __launch_bounds__(256) void qkern(
    const float* __restrict__ z,   // [N][32]
    const float* __restrict__ mu,  // [10][32]
    float* __restrict__ q,         // [N][10]
    int N)
{
    const int tid  = threadIdx.x;
    const int lane = tid & 31;
    const int i    = blockIdx.x * 8 + (tid >> 5);
    if (i >= N) return;

    float zv = z[i * 32 + lane];
    float qm = 0.f, qsum = 0.f;
#pragma unroll
    for (int c = 0; c < 10; ++c) {
        float d = zv - mu[c * 32 + lane];
        float p = d * d;
#pragma unroll
        for (int m = 16; m >= 1; m >>= 1) p += __shfl_xor(p, m, 32);
        // q = (1 + d2/alpha + 1e-8)^-(alpha+1) / 2,  alpha = 0.2
        float t  = 1.0f + p * 5.0f + 1e-8f;
        float qc = powf(t, -1.2f) * 0.5f;
        qsum += qc;
        if (lane == c) qm = qc;
    }
    if (lane < 10) q[i * 10 + lane] = qm / qsum;
}

extern "C" void kernel_launch(void* const* d_in, const int* in_sizes, int n_in,
                              void* d_out, int out_size, void* d_ws, size_t ws_size,
                              hipStream_t stream)
{
    const float* x   = (const float*)d_in[0];   // [10000][3000]
    const float* adj = (const float*)d_in[1];   // [10000][10000]
    const float* W   = (const float*)d_in[2];   // [3000][32]
    const float* b   = (const float*)d_in[3];   // [32]
    const float* mu  = (const float*)d_in[4];   // [10][32]

    const int N = 10000, NFEAT = 3000;
    float* z_out = (float*)d_out;               // [10000][32]
    float* q_out = (float*)d_out + N * NH;      // [10000][10]

    // split-K factor: 32 if workspace allows (42.24 MB), else 16
    const size_t need32 = (size_t)(32 + 1) * N * NH * sizeof(float);
    const int nsplit = (ws_size >= need32) ? 32 : 16;

    float* ws_part    = (float*)d_ws;                            // nsplit*320000
    float* ws_support = (float*)d_ws + (size_t)nsplit * N * NH;  // 320000

    const int total4  = N * NH / 4;             // 80000
    const int rowBlks = (N + TRB - 1) / TRB;    // 79
    const int redBlks = (total4 + 255) / 256;   // 313

    // k-chunk per split, rounded up to a multiple of 8
    const int ch1 = ((NFEAT + nsplit - 1) / nsplit + 7) & ~7;
    const int ch2 = ((N     + nsplit - 1) / nsplit + 7) & ~7;

    // 1) support partials = x @ W
    gemm_stream32<<<dim3(rowBlks, nsplit), 256, 0, stream>>>(
        x, W, ws_part, N, NFEAT, ch1);
    // 2) support = sum partials
    reduce_add<<<redBlks, 256, 0, stream>>>(ws_part, nullptr, ws_support, total4, nsplit);
    // 3) z partials = adj @ support
    gemm_stream32<<<dim3(rowBlks, nsplit), 256, 0, stream>>>(
        adj, ws_support, ws_part, N, N, ch2);
    // 4) z = sum partials + b  -> d_out
    reduce_add<<<redBlks, 256, 0, stream>>>(ws_part, b, z_out, total4, nsplit);
    // 5) q from z -> d_out + 320000
    qkern<<<(N + 7) / 8, 256, 0, stream>>>(z_out, mu, q_out, N);
}

// Round 5
// 759.569 us; speedup vs baseline: 2.2152x; 1.1572x over previous
//
#include <hip/hip_runtime.h>
#include <math.h>

// SimpleGCDEC: z = adj @ (x @ W) + b ; q = student-t soft assignment
// N=10000, NFEAT=3000, NHID=32, K=10, ALPHA=0.2
//
// Streaming split-K GEMM: A (x / adj) global->registers (used once, no LDS
// for A); B (W / support) staged in LDS, 160 rows per round (20 KB).
// R5: 4x4 thread tile with 4-k pipeline windows (two live 16-reg windows,
// not four) to land under the 128-VGPR occupancy boundary. R4 hit VGPR=136
// -> same 2-waves/SIMD bin as R1 (occ 11%, VALU 38%). Pointer+imm-offset
// addressing, peeled last iteration. No launch_bounds min-waves hint
// (R2: (256,4) forced VGPR=64 -> 2 GB scratch spills).

#define NH   32      // NHID
#define SUBK 160     // B rows staged per LDS round (20480 B)
#define TRB  128     // rows per block

// 4 k-steps x 4 rows x 4 cols; bs pre-offset by jg, rows at bs[t*8]
__device__ __forceinline__ void fma4k(const float4* __restrict__ bs,
                                      const float4* a, float acc[4][4])
{
#pragma unroll
    for (int t = 0; t < 4; ++t) {
        float4 b = bs[t * 8];
#pragma unroll
        for (int m = 0; m < 4; ++m) {
            float av = (t == 0) ? a[m].x : (t == 1) ? a[m].y
                     : (t == 2) ? a[m].z : a[m].w;
            acc[m][0] += av * b.x;
            acc[m][1] += av * b.y;
            acc[m][2] += av * b.z;
            acc[m][3] += av * b.w;
        }
    }
}

__global__ __launch_bounds__(256) void gemm_stream32(
    const float* __restrict__ A,   // [M][K], streamed
    const float* __restrict__ B,   // [K][32], LDS-staged
    float* __restrict__ outp,      // [nsplit][M][32] partials
    int M, int K, int CH)          // CH = k-range per split, multiple of 8
{
    __shared__ float Bs[SUBK * NH];          // 20480 B

    const int tid     = threadIdx.x;
    const int rowslot = tid >> 3;            // 0..31
    const int jg      = tid & 7;             // 0..7 (cols jg*4..+3)
    const int row0    = blockIdx.x * TRB;
    const int sy      = blockIdx.y;
    const int k0      = sy * CH;
    const int kspl    = min(CH, K - k0);     // > 0, multiple of 8

    // per-thread A row pointers (row-clamped; stores are guarded below)
    const float* ap[4];
#pragma unroll
    for (int m = 0; m < 4; ++m) {
        int r = row0 + rowslot + (m << 5);
        if (r > M - 1) r = M - 1;
        ap[m] = A + (size_t)r * K + k0;
    }

    float acc[4][4];
#pragma unroll
    for (int m = 0; m < 4; ++m)
#pragma unroll
        for (int j = 0; j < 4; ++j) acc[m][j] = 0.0f;

    for (int kb = 0; kb < kspl; kb += SUBK) {
        const int kcnt = min(SUBK, kspl - kb);   // multiple of 8, >= 8

        // ---- stage B sub-block: kcnt rows x 32 cols, contiguous float4 copy
        {
            const float4* src = (const float4*)(B + (size_t)(k0 + kb) * NH);
            float4* dst = (float4*)Bs;
            for (int i = tid; i < kcnt * 8; i += 256) dst[i] = src[i];
        }
        __syncthreads();

        // ---- stream A: 4-k windows, two live (cur W0 / next W1)
        const float4* p0 = (const float4*)(ap[0] + kb);
        const float4* p1 = (const float4*)(ap[1] + kb);
        const float4* p2 = (const float4*)(ap[2] + kb);
        const float4* p3 = (const float4*)(ap[3] + kb);
        const float4* bs = ((const float4*)Bs) + jg;

        float4 W0[4], W1[4];
        W0[0] = p0[0]; W0[1] = p1[0]; W0[2] = p2[0]; W0[3] = p3[0];

        const int nIter = kcnt >> 3;             // >= 1
        for (int it = 0; it < nIter - 1; ++it) {
            W1[0] = p0[1]; W1[1] = p1[1]; W1[2] = p2[1]; W1[3] = p3[1];
            fma4k(bs, W0, acc);
            W0[0] = p0[2]; W0[1] = p1[2]; W0[2] = p2[2]; W0[3] = p3[2];
            fma4k(bs + 32, W1, acc);
            p0 += 2; p1 += 2; p2 += 2; p3 += 2;
            bs += 64;
        }
        // peeled last 8-k (no W0 reload)
        W1[0] = p0[1]; W1[1] = p1[1]; W1[2] = p2[1]; W1[3] = p3[1];
        fma4k(bs, W0, acc);
        fma4k(bs + 32, W1, acc);

        __syncthreads();
    }

    // ---- store partials (coalesced: one 1024 B wave-store per m)
    float* op = outp + (size_t)sy * M * NH;
#pragma unroll
    for (int m = 0; m < 4; ++m) {
        int gr = row0 + rowslot + (m << 5);
        if (gr < M) {
            float4 v = make_float4(acc[m][0], acc[m][1], acc[m][2], acc[m][3]);
            *(float4*)(op + (size_t)gr * NH + (jg << 2)) = v;
        }
    }
}

__global__ __launch_bounds__(256) void reduce_add(
    const float* __restrict__ parts,  // [nsplit][total4] float4
    const float* __restrict__ bias,   // [32] or nullptr
    float* __restrict__ out,          // [total4] float4
    int total4, int nsplit)
{
    int i = blockIdx.x * blockDim.x + threadIdx.x;
    if (i >= total4) return;
    float4 s = make_float4(0.f, 0.f, 0.f, 0.f);
    for (int p = 0; p < nsplit; ++p) {
        float4 v = ((const float4*)parts)[(size_t)p * total4 + i];
        s.x += v.x; s.y += v.y; s.z += v.z; s.w += v.w;
    }
    if (bias) {
        float4 bv = ((const float4*)bias)[i & 7];   // f4 slot within 32-wide row
        s.x += bv.x; s.y += bv.y; s.z += bv.z; s.w += bv.w;
    }
    ((float4*)out)[i] = s;
}

__global__ __launch_bounds__(256) void qkern(
    const float* __restrict__ z,   // [N][32]
    const float* __restrict__ mu,  // [10][32]
    float* __restrict__ q,         // [N][10]
    int N)
{
    const int tid  = threadIdx.x;
    const int lane = tid & 31;
    const int i    = blockIdx.x * 8 + (tid >> 5);
    if (i >= N) return;

    float zv = z[i * 32 + lane];
    float qm = 0.f, qsum = 0.f;
#pragma unroll
    for (int c = 0; c < 10; ++c) {
        float d = zv - mu[c * 32 + lane];
        float p = d * d;
#pragma unroll
        for (int m = 16; m >= 1; m >>= 1) p += __shfl_xor(p, m, 32);
        // q = (1 + d2/alpha + 1e-8)^-(alpha+1) / 2,  alpha = 0.2
        float t  = 1.0f + p * 5.0f + 1e-8f;
        float qc = powf(t, -1.2f) * 0.5f;
        qsum += qc;
        if (lane == c) qm = qc;
    }
    if (lane < 10) q[i * 10 + lane] = qm / qsum;
}

extern "C" void kernel_launch(void* const* d_in, const int* in_sizes, int n_in,
                              void* d_out, int out_size, void* d_ws, size_t ws_size,
                              hipStream_t stream)
{
    const float* x   = (const float*)d_in[0];   // [10000][3000]
    const float* adj = (const float*)d_in[1];   // [10000][10000]
    const float* W   = (const float*)d_in[2];   // [3000][32]
    const float* b   = (const float*)d_in[3];   // [32]
    const float* mu  = (const float*)d_in[4];   // [10][32]

    const int N = 10000, NFEAT = 3000;
    float* z_out = (float*)d_out;               // [10000][32]
    float* q_out = (float*)d_out + N * NH;      // [10000][10]

    // split-K factor: 32 if workspace allows (42.24 MB), else 16
    const size_t need32 = (size_t)(32 + 1) * N * NH * sizeof(float);
    const int nsplit = (ws_size >= need32) ? 32 : 16;

    float* ws_part    = (float*)d_ws;                            // nsplit*320000
    float* ws_support = (float*)d_ws + (size_t)nsplit * N * NH;  // 320000

    const int total4  = N * NH / 4;             // 80000
    const int rowBlks = (N + TRB - 1) / TRB;    // 79
    const int redBlks = (total4 + 255) / 256;   // 313

    // k-chunk per split, rounded up to a multiple of 8
    const int ch1 = ((NFEAT + nsplit - 1) / nsplit + 7) & ~7;
    const int ch2 = ((N     + nsplit - 1) / nsplit + 7) & ~7;

    // 1) support partials = x @ W
    gemm_stream32<<<dim3(rowBlks, nsplit), 256, 0, stream>>>(
        x, W, ws_part, N, NFEAT, ch1);
    // 2) support = sum partials
    reduce_add<<<redBlks, 256, 0, stream>>>(ws_part, nullptr, ws_support, total4, nsplit);
    // 3) z partials = adj @ support
    gemm_stream32<<<dim3(rowBlks, nsplit), 256, 0, stream>>>(
        adj, ws_support, ws_part, N, N, ch2);
    // 4) z = sum partials + b  -> d_out
    reduce_add<<<redBlks, 256, 0, stream>>>(ws_part, b, z_out, total4, nsplit);
    // 5) q from z -> d_out + 320000
    qkern<<<(N + 7) / 8, 256, 0, stream>>>(z_out, mu, q_out, N);
}

// Round 6
// 747.660 us; speedup vs baseline: 2.2504x; 1.0159x over previous
//
#include <hip/hip_runtime.h>
#include <math.h>

// SimpleGCDEC: z = adj @ (x @ W) + b ; q = student-t soft assignment
// N=10000, NFEAT=3000, NHID=32, K=10, ALPHA=0.2
//
// Streaming split-K GEMM: A (x / adj) global->registers (used once, no LDS
// for A); B (W / support) staged in LDS (broadcast reads, conflict-free).
// R6: latency-distance fix. R5 consumed a prefetched window ~1 segment
// (~200 wall cyc) after issue vs ~900-cyc HBM latency -> 40-50% VALU duty.
// Now: 2 rows x 4 cols per thread (acc 8), FOUR live 4-k windows ->
// consume-to-reload distance ~3.25 segments (~830 wall cyc at 4 waves/SIMD).
// Hand-count ~70 VGPR + slop -> expect ~105 < 128 (4 waves/SIMD bin).
// TRB=64 -> 5024 blocks. No launch_bounds min-waves hint (R2: forced
// VGPR=64 -> 2 GB scratch spills). NOTE: harness ws re-poison fill
// (~245 us, 1.6 GB @ 6.5 TB/s) appears to be counted inside dur_us.

#define NH   32      // NHID
#define SUBK 160     // B rows staged per LDS round (20480 B), mult of 16
#define TRB  64      // rows per block

// one 4-k segment: 2 rows x 4 cols; bs pre-offset by jg, k-rows at bs[t*8]
__device__ __forceinline__ void seg4(const float4* __restrict__ bs,
                                     const float4 w0, const float4 w1,
                                     float acc[2][4])
{
#pragma unroll
    for (int t = 0; t < 4; ++t) {
        float4 b = bs[t * 8];
        float a0 = (t == 0) ? w0.x : (t == 1) ? w0.y : (t == 2) ? w0.z : w0.w;
        float a1 = (t == 0) ? w1.x : (t == 1) ? w1.y : (t == 2) ? w1.z : w1.w;
        acc[0][0] += a0 * b.x; acc[0][1] += a0 * b.y;
        acc[0][2] += a0 * b.z; acc[0][3] += a0 * b.w;
        acc[1][0] += a1 * b.x; acc[1][1] += a1 * b.y;
        acc[1][2] += a1 * b.z; acc[1][3] += a1 * b.w;
    }
}

__global__ __launch_bounds__(256) void gemm_stream32(
    const float* __restrict__ A,   // [M][K], streamed
    const float* __restrict__ B,   // [K][32], LDS-staged
    float* __restrict__ outp,      // [nsplit][M][32] partials
    int M, int K, int CH)          // CH = k-range per split, multiple of 8
{
    __shared__ float Bs[SUBK * NH];          // 20480 B

    const int tid     = threadIdx.x;
    const int rowslot = tid >> 3;            // 0..31
    const int jg      = tid & 7;             // 0..7 (cols jg*4..+3)
    const int row0    = blockIdx.x * TRB;
    const int sy      = blockIdx.y;
    const int k0      = sy * CH;
    const int kspl    = min(CH, K - k0);     // > 0, multiple of 8

    // per-thread A row pointers (row-clamped; stores are guarded below)
    int r0 = row0 + rowslot;       if (r0 > M - 1) r0 = M - 1;
    int r1 = row0 + rowslot + 32;  if (r1 > M - 1) r1 = M - 1;
    const float* ap0 = A + (size_t)r0 * K + k0;
    const float* ap1 = A + (size_t)r1 * K + k0;

    float acc[2][4];
#pragma unroll
    for (int m = 0; m < 2; ++m)
#pragma unroll
        for (int j = 0; j < 4; ++j) acc[m][j] = 0.0f;

    for (int kb = 0; kb < kspl; kb += SUBK) {
        int kcnt = min(SUBK, kspl - kb);     // multiple of 8, >= 8

        // ---- stage B sub-block: kcnt rows x 32 cols, contiguous float4 copy
        {
            const float4* src = (const float4*)(B + (size_t)(k0 + kb) * NH);
            float4* dst = (float4*)Bs;
            for (int i = tid; i < kcnt * 8; i += 256) dst[i] = src[i];
        }
        __syncthreads();

        const float4* q0 = (const float4*)(ap0 + kb);
        const float4* q1 = (const float4*)(ap1 + kb);
        const float4* bs = ((const float4*)Bs) + jg;

        // ---- 8-k pre-step if kcnt % 16 == 8 (shallow, rare)
        if (kcnt & 8) {
            float4 xa = q0[0], xb = q1[0], ya = q0[1], yb = q1[1];
            seg4(bs,      xa, xb, acc);
            seg4(bs + 32, ya, yb, acc);
            q0 += 2; q1 += 2; bs += 64; kcnt -= 8;
        }

        // ---- depth-4 pipelined main: 4 live 4-k windows, 16 k per iter
        if (kcnt) {                          // kcnt multiple of 16, >= 16
            float4 w0a = q0[0], w0b = q1[0], w1a = q0[1], w1b = q1[1];
            float4 w2a = q0[2], w2b = q1[2], w3a = q0[3], w3b = q1[3];
            const int iters = (kcnt - 16) >> 4;
            for (int it = 0; it < iters; ++it) {
                seg4(bs,      w0a, w0b, acc); w0a = q0[4]; w0b = q1[4];
                seg4(bs + 32, w1a, w1b, acc); w1a = q0[5]; w1b = q1[5];
                seg4(bs + 64, w2a, w2b, acc); w2a = q0[6]; w2b = q1[6];
                seg4(bs + 96, w3a, w3b, acc); w3a = q0[7]; w3b = q1[7];
                q0 += 4; q1 += 4; bs += 128;
            }
            // epilogue: consume the last 4 windows, no reload
            seg4(bs,      w0a, w0b, acc);
            seg4(bs + 32, w1a, w1b, acc);
            seg4(bs + 64, w2a, w2b, acc);
            seg4(bs + 96, w3a, w3b, acc);
        }
        __syncthreads();
    }

    // ---- store partials (coalesced: one 1024 B wave-store per row-group)
    float* op = outp + (size_t)sy * M * NH;
    {
        int gr = row0 + rowslot;
        if (gr < M) {
            float4 v = make_float4(acc[0][0], acc[0][1], acc[0][2], acc[0][3]);
            *(float4*)(op + (size_t)gr * NH + (jg << 2)) = v;
        }
        gr = row0 + rowslot + 32;
        if (gr < M) {
            float4 v = make_float4(acc[1][0], acc[1][1], acc[1][2], acc[1][3]);
            *(float4*)(op + (size_t)gr * NH + (jg << 2)) = v;
        }
    }
}

__global__ __launch_bounds__(256) void reduce_add(
    const float* __restrict__ parts,  // [nsplit][total4] float4
    const float* __restrict__ bias,   // [32] or nullptr
    float* __restrict__ out,          // [total4] float4
    int total4, int nsplit)
{
    int i = blockIdx.x * blockDim.x + threadIdx.x;
    if (i >= total4) return;
    float4 s = make_float4(0.f, 0.f, 0.f, 0.f);
    for (int p = 0; p < nsplit; ++p) {
        float4 v = ((const float4*)parts)[(size_t)p * total4 + i];
        s.x += v.x; s.y += v.y; s.z += v.z; s.w += v.w;
    }
    if (bias) {
        float4 bv = ((const float4*)bias)[i & 7];   // f4 slot within 32-wide row
        s.x += bv.x; s.y += bv.y; s.z += bv.z; s.w += bv.w;
    }
    ((float4*)out)[i] = s;
}

__global__ __launch_bounds__(256) void qkern(
    const float* __restrict__ z,   // [N][32]
    const float* __restrict__ mu,  // [10][32]
    float* __restrict__ q,         // [N][10]
    int N)
{
    const int tid  = threadIdx.x;
    const int lane = tid & 31;
    const int i    = blockIdx.x * 8 + (tid >> 5);
    if (i >= N) return;

    float zv = z[i * 32 + lane];
    float qm = 0.f, qsum = 0.f;
#pragma unroll
    for (int c = 0; c < 10; ++c) {
        float d = zv - mu[c * 32 + lane];
        float p = d * d;
#pragma unroll
        for (int m = 16; m >= 1; m >>= 1) p += __shfl_xor(p, m, 32);
        // q = (1 + d2/alpha + 1e-8)^-(alpha+1) / 2,  alpha = 0.2
        float t  = 1.0f + p * 5.0f + 1e-8f;
        float qc = powf(t, -1.2f) * 0.5f;
        qsum += qc;
        if (lane == c) qm = qc;
    }
    if (lane < 10) q[i * 10 + lane] = qm / qsum;
}

extern "C" void kernel_launch(void* const* d_in, const int* in_sizes, int n_in,
                              void* d_out, int out_size, void* d_ws, size_t ws_size,
                              hipStream_t stream)
{
    const float* x   = (const float*)d_in[0];   // [10000][3000]
    const float* adj = (const float*)d_in[1];   // [10000][10000]
    const float* W   = (const float*)d_in[2];   // [3000][32]
    const float* b   = (const float*)d_in[3];   // [32]
    const float* mu  = (const float*)d_in[4];   // [10][32]

    const int N = 10000, NFEAT = 3000;
    float* z_out = (float*)d_out;               // [10000][32]
    float* q_out = (float*)d_out + N * NH;      // [10000][10]

    // split-K factor: 32 if workspace allows (42.24 MB), else 16
    const size_t need32 = (size_t)(32 + 1) * N * NH * sizeof(float);
    const int nsplit = (ws_size >= need32) ? 32 : 16;

    float* ws_part    = (float*)d_ws;                            // nsplit*320000
    float* ws_support = (float*)d_ws + (size_t)nsplit * N * NH;  // 320000

    const int total4  = N * NH / 4;             // 80000
    const int rowBlks = (N + TRB - 1) / TRB;    // 157
    const int redBlks = (total4 + 255) / 256;   // 313

    // k-chunk per split, rounded up to a multiple of 8
    const int ch1 = ((NFEAT + nsplit - 1) / nsplit + 7) & ~7;
    const int ch2 = ((N     + nsplit - 1) / nsplit + 7) & ~7;

    // 1) support partials = x @ W
    gemm_stream32<<<dim3(rowBlks, nsplit), 256, 0, stream>>>(
        x, W, ws_part, N, NFEAT, ch1);
    // 2) support = sum partials
    reduce_add<<<redBlks, 256, 0, stream>>>(ws_part, nullptr, ws_support, total4, nsplit);
    // 3) z partials = adj @ support
    gemm_stream32<<<dim3(rowBlks, nsplit), 256, 0, stream>>>(
        adj, ws_support, ws_part, N, N, ch2);
    // 4) z = sum partials + b  -> d_out
    reduce_add<<<redBlks, 256, 0, stream>>>(ws_part, b, z_out, total4, nsplit);
    // 5) q from z -> d_out + 320000
    qkern<<<(N + 7) / 8, 256, 0, stream>>>(z_out, mu, q_out, N);
}